// Round 2
// 158.356 us; speedup vs baseline: 1.0034x; 1.0034x over previous
//
#include <hip/hip_runtime.h>
#include <hip/hip_bf16.h>

// Embedding gather: out[i, :] = weight[idx[i], :]
// idx: [8*4096] int32, weight: [50257, 512] fp32, out: [8*4096, 512] fp32.
//
// v2 structure: 32 threads per row, 4 float4 per thread (cols at stride 32).
//  - 4 independent weight loads in flight per thread (64 B MLP vs 16 B in v1)
//  - idx[row] loaded once per 32 threads (was once per 128)
//  - nontemporal stores: output is write-once, keep L2 for weight rows
//  - grid 4096 blocks (was 16384): less dispatch churn
// Coalescing: lanes 0..31 of a wave share a row; each load instruction covers
// a contiguous 512 B segment per 32-lane half (2 segments/wave) - fully coalesced.
//
// NB: __builtin_nontemporal_store requires a NATIVE vector type, not
// HIP_vector_type<float,4> — use ext_vector_type(4) and cast.

#define EMBED_F4 128          // 512 floats / 4
#define N_IDX    (8 * 4096)   // 32768 indices
#define THREADS_PER_ROW 32
#define F4_PER_THREAD   4     // 32 * 4 = 128 = EMBED_F4
#define TOTAL_THREADS (N_IDX * THREADS_PER_ROW)   // 1,048,576

typedef float f4 __attribute__((ext_vector_type(4)));

__global__ __launch_bounds__(256) void Embedding_60327110640045_kernel(
    const int* __restrict__ idx,
    const f4* __restrict__ weight,   // [50257 * 128] float4
    f4* __restrict__ out)            // [32768 * 128] float4
{
    int tid  = blockIdx.x * blockDim.x + threadIdx.x;   // < 1,048,576 exactly
    int row  = tid >> 5;          // which index (32 threads per row)
    int lane = tid & 31;          // col base within the row

    int w_row = idx[row];

    const f4* __restrict__ wsrc = weight + (size_t)w_row * EMBED_F4 + lane;
    f4*       __restrict__ dst  = out    + (size_t)row   * EMBED_F4 + lane;

    // 4 independent loads in flight, then 4 streaming stores.
    f4 a = wsrc[0];
    f4 b = wsrc[32];
    f4 c = wsrc[64];
    f4 d = wsrc[96];

    __builtin_nontemporal_store(a, dst + 0);
    __builtin_nontemporal_store(b, dst + 32);
    __builtin_nontemporal_store(c, dst + 64);
    __builtin_nontemporal_store(d, dst + 96);
}

extern "C" void kernel_launch(void* const* d_in, const int* in_sizes, int n_in,
                              void* d_out, int out_size, void* d_ws, size_t ws_size,
                              hipStream_t stream) {
    const int* idx    = (const int*)d_in[0];
    const f4*  weight = (const f4*)d_in[1];
    f4*        out    = (f4*)d_out;

    const int block = 256;
    const int grid  = TOTAL_THREADS / block;   // 4096 blocks, exact
    Embedding_60327110640045_kernel<<<grid, block, 0, stream>>>(idx, weight, out);
}